// Round 1
// baseline (4102.766 us; speedup 1.0000x reference)
//
#include <hip/hip_runtime.h>

#define NB 512
#define ND 32
#define NH 256
#define NSTEPS 8

// Dopri5 tableau
__device__ __constant__ float Atab[6][5] = {
    {0.f, 0.f, 0.f, 0.f, 0.f},
    {0.2f, 0.f, 0.f, 0.f, 0.f},
    {3.f/40.f, 9.f/40.f, 0.f, 0.f, 0.f},
    {44.f/45.f, -56.f/15.f, 32.f/9.f, 0.f, 0.f},
    {19372.f/6561.f, -25360.f/2187.f, 64448.f/6561.f, -212.f/729.f, 0.f},
    {9017.f/3168.f, -355.f/33.f, 46732.f/5247.f, 49.f/176.f, -5103.f/18656.f}
};
__device__ __constant__ float Btab[6] = {
    35.f/384.f, 0.f, 500.f/1113.f, 125.f/192.f, -2187.f/6784.f, 11.f/84.f
};
__device__ __constant__ float Ctab[6] = {0.f, 0.2f, 0.3f, 0.8f, 8.f/9.f, 1.f};

// One block per batch element. 256 threads = 4 waves.
// Thread j owns hidden unit j in layers 1/2; (i=tid>>3, d=tid&7 quad) for J.
extern "C" __global__ void __launch_bounds__(256, 2)
node_kernel(const float* __restrict__ x_in,
            const float* __restrict__ W1, const float* __restrict__ b1,
            const float* __restrict__ W2, const float* __restrict__ b2,
            const float* __restrict__ W3, const float* __restrict__ b3,
            float* __restrict__ out)
{
    const int bid = blockIdx.x;
    const int tid = threadIdx.x;

    // st: per-stage staging buffer, dual use:
    //   phase A: st[k][i] = W1[i][k]*s1[k] (i<32), st[k][32] = h1[k]
    //   phase B: st[j][i] = T[i][j]*s2[j]  (i<32), st[j][32] = h2[j]
    __shared__ __align__(16) float st[NH][36];
    __shared__ float xs[ND];       // stage input x
    __shared__ float xc[ND];       // carry x
    __shared__ float ksb[6][ND];   // stage dxdt (already negated)
    __shared__ float sck[6][3];    // per-stage scalar derivs: [-tr, |vf|^2, frob]
    __shared__ float red[12];      // cross-wave reduction
    __shared__ float csc[3];       // carry scalars: log_det, vf_norm, jac_frob

    if (tid < ND) xc[tid] = x_in[bid * ND + tid];
    if (tid < 3)  csc[tid] = 0.f;
    __syncthreads();

    const float dt = 1.0f / 8.0f;

    for (int n = 0; n < NSTEPS; ++n) {
        const float t0 = (float)n * dt;
        for (int s = 0; s < 6; ++s) {
            // ---- stage input: xs = xc + dt * sum_j A[s][j] * k_j ----
            if (tid < ND) {
                float v = xc[tid];
                for (int j = 0; j < s; ++j) v += dt * Atab[s][j] * ksb[j][tid];
                xs[tid] = v;
            }
            __syncthreads();
            const float t_eff = 1.0f - (t0 + Ctab[s] * dt);  // inverse-time vf

            // ---- layer 1 (thread j): h1_pre = [x,t] @ W1[:,j] + b1 ----
            float w1c[ND];
            float pre = b1[tid] + t_eff * W1[32 * NH + tid];
            #pragma unroll
            for (int i = 0; i < ND; ++i) {
                const float w = W1[i * NH + tid];
                w1c[i] = w;
                pre += xs[i] * w;
            }
            const float h1 = tanhf(pre);
            const float s1 = 1.f - h1 * h1;
            #pragma unroll
            for (int i = 0; i < ND; ++i) st[tid][i] = w1c[i] * s1;
            st[tid][32] = h1;
            __syncthreads();

            // ---- layer 2 k-loop: T[i][j] = sum_k R[i][k]*W2[k][j]; h2_pre rides along ----
            float acc[33];
            #pragma unroll
            for (int i = 0; i < 33; ++i) acc[i] = 0.f;
            const float* w2p = W2 + tid;
            const float4* stq = (const float4*)&st[0][0];
            float w2a = w2p[0];
            float w2b = w2p[NH];
            for (int k = 0; k < NH; ++k) {
                const float w2 = w2a;
                w2a = w2b;
                const int kn = (k + 2 < NH) ? (k + 2) : (NH - 1);
                w2b = w2p[kn * NH];
                float4 rq[9];
                #pragma unroll
                for (int q = 0; q < 9; ++q) rq[q] = stq[k * 9 + q];  // broadcast reads
                #pragma unroll
                for (int q = 0; q < 8; ++q) {
                    acc[4*q+0] += rq[q].x * w2;
                    acc[4*q+1] += rq[q].y * w2;
                    acc[4*q+2] += rq[q].z * w2;
                    acc[4*q+3] += rq[q].w * w2;
                }
                acc[32] += rq[8].x * w2;  // h1[k] * W2[k][j]
            }
            __syncthreads();

            // ---- activation 2, write Ts back ----
            const float h2  = tanhf(acc[32] + b2[tid]);
            const float s2v = 1.f - h2 * h2;
            #pragma unroll
            for (int i = 0; i < ND; ++i) st[tid][i] = acc[i] * s2v;
            st[tid][32] = h2;
            __syncthreads();

            // ---- J[i][d] = sum_j Ts[j][i] * W3[j][d]; thread owns (ii, d0..d0+3) ----
            const int ii = tid >> 3;
            const int d0 = (tid & 7) * 4;
            float jac0 = 0.f, jac1 = 0.f, jac2 = 0.f, jac3 = 0.f;
            for (int j = 0; j < NH; ++j) {
                const float ts = st[j][ii];
                const float4 w3 = *(const float4*)(W3 + j * ND + d0);
                jac0 += ts * w3.x; jac1 += ts * w3.y;
                jac2 += ts * w3.z; jac3 += ts * w3.w;
            }
            // ---- primal out on threads 0..31: vf_d = sum_j h2[j]*W3[j][d] + b3 ----
            float dx = 0.f;
            if (tid < ND) {
                float o = b3[tid];
                for (int j = 0; j < NH; ++j) o += st[j][32] * W3[j * ND + tid];
                dx = -o;                 // forward direction negates vf
                ksb[s][tid] = dx;
            }

            // ---- reductions: frob, trace, |vf|^2 ----
            float frobp = jac0*jac0 + jac1*jac1 + jac2*jac2 + jac3*jac3;
            float trp = 0.f;
            const int dd = ii - d0;
            if (dd >= 0 && dd < 4)
                trp = (dd == 0) ? jac0 : (dd == 1) ? jac1 : (dd == 2) ? jac2 : jac3;
            float vfp = dx * dx;
            #pragma unroll
            for (int off = 32; off > 0; off >>= 1) {
                frobp += __shfl_down(frobp, off, 64);
                trp   += __shfl_down(trp,   off, 64);
                vfp   += __shfl_down(vfp,   off, 64);
            }
            const int wid = tid >> 6;
            if ((tid & 63) == 0) {
                red[wid*3+0] = frobp; red[wid*3+1] = trp; red[wid*3+2] = vfp;
            }
            __syncthreads();
            if (tid == 0) {
                float fa = 0.f, fb = 0.f, fc = 0.f;
                #pragma unroll
                for (int w = 0; w < 4; ++w) {
                    fa += red[w*3+0]; fb += red[w*3+1]; fc += red[w*3+2];
                }
                sck[s][0] = -fb;   // d(log_det)/dt = -tr(J)
                sck[s][1] = fc;    // |dxdt|^2
                sck[s][2] = fa;    // sum(J*J)
            }
            __syncthreads();
        }

        // ---- carry update: y += dt * sum_s B[s] * k_s ----
        if (tid < ND) {
            float v = xc[tid];
            #pragma unroll
            for (int s = 0; s < 6; ++s) v += dt * Btab[s] * ksb[s][tid];
            xc[tid] = v;
        }
        if (tid == 0) {
            float a = csc[0], b = csc[1], c = csc[2];
            #pragma unroll
            for (int s = 0; s < 6; ++s) {
                a += dt * Btab[s] * sck[s][0];
                b += dt * Btab[s] * sck[s][1];
                c += dt * Btab[s] * sck[s][2];
            }
            csc[0] = a; csc[1] = b; csc[2] = c;
        }
        __syncthreads();
    }

    // ---- pack output: (B, D+3) ----
    if (tid < ND) out[bid * 35 + tid] = xc[tid];
    if (tid == 0) {
        out[bid * 35 + 32] = csc[0];
        out[bid * 35 + 33] = csc[1];
        out[bid * 35 + 34] = csc[2];
    }
}

extern "C" void kernel_launch(void* const* d_in, const int* in_sizes, int n_in,
                              void* d_out, int out_size, void* d_ws, size_t ws_size,
                              hipStream_t stream) {
    const float* x  = (const float*)d_in[0];
    const float* W1 = (const float*)d_in[1];
    const float* b1 = (const float*)d_in[2];
    const float* W2 = (const float*)d_in[3];
    const float* b2 = (const float*)d_in[4];
    const float* W3 = (const float*)d_in[5];
    const float* b3 = (const float*)d_in[6];
    float* outp = (float*)d_out;
    hipLaunchKernelGGL(node_kernel, dim3(NB), dim3(256), 0, stream,
                       x, W1, b1, W2, b2, W3, b3, outp);
}

// Round 2
// 487.323 us; speedup vs baseline: 8.4190x; 8.4190x over previous
//
#include <hip/hip_runtime.h>

#define NB 512
#define ND 32
#define NH 256
#define NSTEPS 8
#define LAP 264   // padded LDS row stride in bf16 elems (stride 528B -> 2-way bank alias, free)

typedef __attribute__((ext_vector_type(8))) short short8;
typedef __attribute__((ext_vector_type(4))) short short4v;
typedef __attribute__((ext_vector_type(4))) float f32x4;

__device__ __constant__ float Atab[6][5] = {
    {0.f, 0.f, 0.f, 0.f, 0.f},
    {0.2f, 0.f, 0.f, 0.f, 0.f},
    {3.f/40.f, 9.f/40.f, 0.f, 0.f, 0.f},
    {44.f/45.f, -56.f/15.f, 32.f/9.f, 0.f, 0.f},
    {19372.f/6561.f, -25360.f/2187.f, 64448.f/6561.f, -212.f/729.f, 0.f},
    {9017.f/3168.f, -355.f/33.f, 46732.f/5247.f, 49.f/176.f, -5103.f/18656.f}
};
__device__ __constant__ float Btab[6] = {
    35.f/384.f, 0.f, 500.f/1113.f, 125.f/192.f, -2187.f/6784.f, 11.f/84.f
};
__device__ __constant__ float Ctab[6] = {0.f, 0.2f, 0.3f, 0.8f, 8.f/9.f, 1.f};

static __device__ __forceinline__ short f2bf(float f){
    __bf16 h = (__bf16)f;
    return __builtin_bit_cast(short, h);
}

// One block per batch element; 4 waves.
// T^T GEMM: M=j(256, 4 Mtiles/wave), N=i(48: 32 tangent rows + h1 row + pad), K=k(256).
// A-operand = W2 fragments resident in registers (identical bit-layout to W2-as-B).
extern "C" __global__ void __launch_bounds__(256, 2)
node_kernel(const float* __restrict__ x_in,
            const float* __restrict__ W1, const float* __restrict__ b1,
            const float* __restrict__ W2, const float* __restrict__ b2,
            const float* __restrict__ W3, const float* __restrict__ b3,
            float* __restrict__ out)
{
    __shared__ __align__(16) short LA [48*LAP];  // A^T source: [i][k] bf16 (row32 = h1)
    __shared__ __align__(16) short LTs[48*LAP];  // Ts^T source: [i][j] bf16 (row32 = h2)
    __shared__ __align__(16) short W3T[32*LAP];  // [d][j] bf16
    __shared__ __align__(16) float h2pre[NH];
    __shared__ __align__(16) float s1_s[NH];
    __shared__ __align__(16) float s2_s[NH];
    __shared__ __align__(16) float xs_s[ND];
    __shared__ __align__(16) float xc_s[ND];
    __shared__ __align__(16) float ksb[6][ND];
    __shared__ float sck[6][3];
    __shared__ float red[4][3];
    __shared__ float csc[3];

    const int bid = blockIdx.x;
    const int tid = threadIdx.x;
    const int w = tid >> 6;        // wave id
    const int l = tid & 63;        // lane
    const int g = (tid >> 4) & 3;  // lane group (l>>4)
    const int c = tid & 15;        // lane&15

    // ---- one-time: W2 fragments into registers ----
    // frag (m,kk): value W2[kk*32+g*8+e][w*64+m*16+c]
    short8 w2f[4][8];
    #pragma unroll
    for (int m = 0; m < 4; ++m) {
        const int j = w*64 + m*16 + c;
        #pragma unroll
        for (int kk = 0; kk < 8; ++kk) {
            const int k0 = kk*32 + g*8;
            short8 f;
            #pragma unroll
            for (int e = 0; e < 8; ++e) f[e] = f2bf(W2[(k0+e)*NH + j]);
            w2f[m][kk] = f;
        }
    }
    // ---- one-time: W3T[d][j] = W3[j][d] ----
    {
        const int d = tid >> 3, j0 = (tid & 7) * 32;
        #pragma unroll
        for (int q = 0; q < 32; ++q)
            W3T[d*LAP + j0 + q] = f2bf(W3[(j0+q)*ND + d]);
    }
    // zero the never-written pad rows (avoid stale-NaN LDS feeding MFMA)
    for (int q = tid; q < 15*LAP; q += 256) { LA[33*LAP + q] = 0; LTs[33*LAP + q] = 0; }

    if (tid < ND) xc_s[tid] = x_in[bid*ND + tid];
    if (tid < 3)  csc[tid] = 0.f;
    __syncthreads();

    const float dt = 0.125f;

    for (int n = 0; n < NSTEPS; ++n) {
        const float t0 = (float)n * dt;
        for (int sg = 0; sg < 6; ++sg) {
            // ---- stage input ----
            if (tid < ND) {
                float v = xc_s[tid];
                for (int q = 0; q < sg; ++q) v += dt * Atab[sg][q] * ksb[q][tid];
                xs_s[tid] = v;
            }
            __syncthreads();
            const float t_eff = 1.0f - (t0 + Ctab[sg]*dt);

            // ---- layer 1: thread = hidden unit k ----
            {
                float pre = b1[tid] + t_eff * W1[32*NH + tid];
                #pragma unroll
                for (int q = 0; q < 8; ++q) {
                    f32x4 xq = *(const f32x4*)&xs_s[q*4];
                    pre += xq[0] * W1[(q*4+0)*NH + tid];
                    pre += xq[1] * W1[(q*4+1)*NH + tid];
                    pre += xq[2] * W1[(q*4+2)*NH + tid];
                    pre += xq[3] * W1[(q*4+3)*NH + tid];
                }
                const float h1 = tanhf(pre);
                s1_s[tid] = 1.f - h1*h1;
                LA[32*LAP + tid] = f2bf(h1);
            }
            __syncthreads();

            // ---- A-build rows 0..31: LA[i][k] = W1[i][k]*s1[k] (bf16) ----
            {
                const int i = tid >> 3, c0 = (tid & 7) * 32;
                const float* wr = W1 + i*NH + c0;
                short* dst = LA + i*LAP + c0;
                #pragma unroll
                for (int q = 0; q < 8; ++q) {
                    f32x4 wq = *(const f32x4*)(wr + q*4);
                    f32x4 sq = *(const f32x4*)(s1_s + c0 + q*4);
                    short4v p;
                    p[0] = f2bf(wq[0]*sq[0]); p[1] = f2bf(wq[1]*sq[1]);
                    p[2] = f2bf(wq[2]*sq[2]); p[3] = f2bf(wq[3]*sq[3]);
                    *(short4v*)(dst + q*4) = p;
                }
            }
            __syncthreads();

            // ---- T^T GEMM: acc[m][nt] = T^T tile (j = w*64+m*16+g*4+r, i = nt*16+c) ----
            f32x4 acc[4][3];
            #pragma unroll
            for (int m = 0; m < 4; ++m)
                #pragma unroll
                for (int q = 0; q < 3; ++q) acc[m][q] = (f32x4){0.f,0.f,0.f,0.f};
            #pragma unroll
            for (int kk = 0; kk < 8; ++kk) {
                const int ko = kk*32 + g*8;
                short8 fA0 = *(const short8*)(LA + ( 0 + c)*LAP + ko);
                short8 fA1 = *(const short8*)(LA + (16 + c)*LAP + ko);
                short8 fA2 = *(const short8*)(LA + (32 + c)*LAP + ko);
                #pragma unroll
                for (int m = 0; m < 4; ++m) {
                    acc[m][0] = __builtin_amdgcn_mfma_f32_16x16x32_bf16(w2f[m][kk], fA0, acc[m][0], 0,0,0);
                    acc[m][1] = __builtin_amdgcn_mfma_f32_16x16x32_bf16(w2f[m][kk], fA1, acc[m][1], 0,0,0);
                    acc[m][2] = __builtin_amdgcn_mfma_f32_16x16x32_bf16(w2f[m][kk], fA2, acc[m][2], 0,0,0);
                }
            }
            // ---- h2_pre = T^T[j][32] (col 0 of Ntile 2) ----
            if (c == 0) {
                #pragma unroll
                for (int m = 0; m < 4; ++m)
                    *(f32x4*)&h2pre[w*64 + m*16 + g*4] = acc[m][2];
            }
            __syncthreads();
            // ---- h2 / s2 ----
            {
                const float h2 = tanhf(h2pre[tid] + b2[tid]);
                s2_s[tid] = 1.f - h2*h2;
                LTs[32*LAP + tid] = f2bf(h2);
            }
            __syncthreads();
            // ---- Ts^T store: LTs[i][j] = T^T[j][i]*s2[j], contiguous b64 writes ----
            #pragma unroll
            for (int m = 0; m < 4; ++m) {
                const int j0 = w*64 + m*16 + g*4;
                f32x4 s2q = *(const f32x4*)&s2_s[j0];
                #pragma unroll
                for (int q = 0; q < 2; ++q) {
                    f32x4 v = acc[m][q] * s2q;
                    short4v p;
                    p[0] = f2bf(v[0]); p[1] = f2bf(v[1]); p[2] = f2bf(v[2]); p[3] = f2bf(v[3]);
                    *(short4v*)(LTs + (q*16 + c)*LAP + j0) = p;
                }
            }
            __syncthreads();

            // ---- J^T GEMM: J^T[d][i] = sum_j W3T[d][j]*LTs[i][j]; tiles split over waves ----
            int mt0, nt0, mt1, nt1, np;
            if      (w == 0) { mt0=0; nt0=0; mt1=0; nt1=0; np=1; }
            else if (w == 1) { mt0=0; nt0=1; mt1=1; nt1=2; np=2; }
            else if (w == 2) { mt0=1; nt0=0; mt1=0; nt1=2; np=2; }
            else             { mt0=1; nt0=1; mt1=0; nt1=0; np=1; }
            f32x4 ja = (f32x4){0,0,0,0}, jb = (f32x4){0,0,0,0};
            #pragma unroll
            for (int kk = 0; kk < 8; ++kk) {
                const int ko = kk*32 + g*8;
                short8 a0  = *(const short8*)(W3T + (mt0*16 + c)*LAP + ko);
                short8 bb0 = *(const short8*)(LTs + (nt0*16 + c)*LAP + ko);
                ja = __builtin_amdgcn_mfma_f32_16x16x32_bf16(a0, bb0, ja, 0,0,0);
                if (np == 2) {
                    short8 a1  = *(const short8*)(W3T + (mt1*16 + c)*LAP + ko);
                    short8 bb1 = *(const short8*)(LTs + (nt1*16 + c)*LAP + ko);
                    jb = __builtin_amdgcn_mfma_f32_16x16x32_bf16(a1, bb1, jb, 0,0,0);
                }
            }

            float frobp = 0.f, trp = 0.f, vfp = 0.f;
            auto jproc = [&](const f32x4& jv, int mt, int nt) {
                if (nt == 2) {
                    if (c == 0) {              // col i==32: primal vf rows d
                        const int d0 = mt*16 + g*4;
                        const f32x4 b3q = *(const f32x4*)(b3 + d0);
                        f32x4 dx;
                        dx[0] = -(jv[0] + b3q[0]); dx[1] = -(jv[1] + b3q[1]);
                        dx[2] = -(jv[2] + b3q[2]); dx[3] = -(jv[3] + b3q[3]);
                        *(f32x4*)&ksb[sg][d0] = dx;
                        vfp += dx[0]*dx[0] + dx[1]*dx[1] + dx[2]*dx[2] + dx[3]*dx[3];
                    }
                } else {                        // d<32, i<32: Jacobian proper
                    frobp += jv[0]*jv[0] + jv[1]*jv[1] + jv[2]*jv[2] + jv[3]*jv[3];
                    if (mt == nt) {
                        const int dd = c - g*4;
                        if (dd >= 0 && dd < 4)
                            trp += (dd==0) ? jv[0] : (dd==1) ? jv[1] : (dd==2) ? jv[2] : jv[3];
                    }
                }
            };
            jproc(ja, mt0, nt0);
            if (np == 2) jproc(jb, mt1, nt1);

            #pragma unroll
            for (int off = 32; off > 0; off >>= 1) {
                frobp += __shfl_down(frobp, off, 64);
                trp   += __shfl_down(trp,   off, 64);
                vfp   += __shfl_down(vfp,   off, 64);
            }
            if (l == 0) { red[w][0] = frobp; red[w][1] = trp; red[w][2] = vfp; }
            __syncthreads();
            if (tid == 0) {
                float fa = 0.f, fb = 0.f, fc = 0.f;
                #pragma unroll
                for (int q = 0; q < 4; ++q) { fa += red[q][0]; fb += red[q][1]; fc += red[q][2]; }
                sck[sg][0] = -fb;   // d(log_det)/dt = -tr(J)
                sck[sg][1] = fc;    // |dxdt|^2
                sck[sg][2] = fa;    // sum(J*J)
            }
        }

        // ---- carry update ----
        __syncthreads();
        if (tid < ND) {
            float v = xc_s[tid];
            #pragma unroll
            for (int sg = 0; sg < 6; ++sg) v += dt * Btab[sg] * ksb[sg][tid];
            xc_s[tid] = v;
        }
        if (tid == 0) {
            float a = csc[0], b = csc[1], cq = csc[2];
            #pragma unroll
            for (int sg = 0; sg < 6; ++sg) {
                a  += dt * Btab[sg] * sck[sg][0];
                b  += dt * Btab[sg] * sck[sg][1];
                cq += dt * Btab[sg] * sck[sg][2];
            }
            csc[0] = a; csc[1] = b; csc[2] = cq;
        }
        __syncthreads();
    }

    if (tid < ND) out[bid*35 + tid] = xc_s[tid];
    if (tid == 0) {
        out[bid*35 + 32] = csc[0];
        out[bid*35 + 33] = csc[1];
        out[bid*35 + 34] = csc[2];
    }
}

extern "C" void kernel_launch(void* const* d_in, const int* in_sizes, int n_in,
                              void* d_out, int out_size, void* d_ws, size_t ws_size,
                              hipStream_t stream) {
    const float* x  = (const float*)d_in[0];
    const float* W1 = (const float*)d_in[1];
    const float* b1 = (const float*)d_in[2];
    const float* W2 = (const float*)d_in[3];
    const float* b2 = (const float*)d_in[4];
    const float* W3 = (const float*)d_in[5];
    const float* b3 = (const float*)d_in[6];
    float* outp = (float*)d_out;
    hipLaunchKernelGGL(node_kernel, dim3(NB), dim3(256), 0, stream,
                       x, W1, b1, W2, b2, W3, b3, outp);
}

// Round 3
// 336.989 us; speedup vs baseline: 12.1748x; 1.4461x over previous
//
#include <hip/hip_runtime.h>

#define NB 512
#define ND 32
#define NH 256
#define NSTEPS 8

typedef __attribute__((ext_vector_type(8))) short short8;
typedef __attribute__((ext_vector_type(4))) short short4v;
typedef __attribute__((ext_vector_type(4))) float f32x4;

__device__ __constant__ float Atab[6][5] = {
    {0.f, 0.f, 0.f, 0.f, 0.f},
    {0.2f, 0.f, 0.f, 0.f, 0.f},
    {3.f/40.f, 9.f/40.f, 0.f, 0.f, 0.f},
    {44.f/45.f, -56.f/15.f, 32.f/9.f, 0.f, 0.f},
    {19372.f/6561.f, -25360.f/2187.f, 64448.f/6561.f, -212.f/729.f, 0.f},
    {9017.f/3168.f, -355.f/33.f, 46732.f/5247.f, 49.f/176.f, -5103.f/18656.f}
};
__device__ __constant__ float Btab[6] = {
    35.f/384.f, 0.f, 500.f/1113.f, 125.f/192.f, -2187.f/6784.f, 11.f/84.f
};
__device__ __constant__ float Ctab[6] = {0.f, 0.2f, 0.3f, 0.8f, 8.f/9.f, 1.f};

static __device__ __forceinline__ short f2bf(float f){
    __bf16 h = (__bf16)f;
    return __builtin_bit_cast(short, h);
}
static __device__ __forceinline__ float bf_lo(unsigned p){
    return __builtin_bit_cast(float, p << 16);
}
static __device__ __forceinline__ float bf_hi(unsigned p){
    return __builtin_bit_cast(float, p & 0xffff0000u);
}
static __device__ __forceinline__ float fast_tanh(float x){
    float e = __expf(2.f * x);
    return 1.f - 2.f / (e + 1.f);
}

// XOR-swizzled LDS addressing: row stride 512B, byte ^= (row&7)<<4.
#define SWZ(base, row, byte) ((base) + ((row) << 9) + ((byte) ^ (((row) & 7) << 4)))

// One block per batch element; 4 waves (256 threads).
// T^T GEMM: M=j(256, 4 Mtiles/wave), N=i(48: 32 tangent + h1 + pad), K=256.
// W2 fragments register-resident (A-operand bit-layout == W2-as-B layout).
extern "C" __global__ void __launch_bounds__(256, 1)
node_kernel(const float* __restrict__ x_in,
            const float* __restrict__ W1, const float* __restrict__ b1,
            const float* __restrict__ W2, const float* __restrict__ b2,
            const float* __restrict__ W3, const float* __restrict__ b3,
            float* __restrict__ out)
{
    __shared__ __align__(16) short LA [48*256];  // A^T, then reused as Ts^T
    __shared__ __align__(16) short W3T[32*256];  // [d][j] bf16, swizzled
    __shared__ __align__(16) float h2pre[NH];
    __shared__ __align__(16) float s2_s[NH];
    __shared__ __align__(16) float xs_s[ND];
    __shared__ __align__(16) float xc_s[ND];
    __shared__ __align__(16) float ksb[6][ND];
    __shared__ float sck[6][3];
    __shared__ float red[4][3];
    __shared__ float csc[3];

    const int bid = blockIdx.x;
    const int tid = threadIdx.x;
    const int w = tid >> 6;        // wave id
    const int l = tid & 63;        // lane
    const int g = (tid >> 4) & 3;  // lane group
    const int c = tid & 15;        // lane&15

    char* LAc = (char*)LA;
    char* W3c = (char*)W3T;
    const int swc = (c & 7) << 4;  // read-side swizzle (row&7 == c&7 for all tiles)

    // ---- one-time: W2 fragments into registers ----
    // frag (m,kk): value W2[kk*32+g*8+e][w*64+m*16+c]
    short8 w2f[4][8];
    #pragma unroll
    for (int m = 0; m < 4; ++m) {
        const int j = w*64 + m*16 + c;
        #pragma unroll
        for (int kk = 0; kk < 8; ++kk) {
            const int k0 = kk*32 + g*8;
            short8 f;
            #pragma unroll
            for (int e = 0; e < 8; ++e) f[e] = f2bf(W2[(k0+e)*NH + j]);
            w2f[m][kk] = f;
        }
    }
    // ---- one-time: W1 column tid packed bf16 into registers ----
    unsigned w1p[16];
    float w1t, b1u;
    {
        #pragma unroll
        for (int q = 0; q < 16; ++q) {
            unsigned lo = (unsigned)(unsigned short)f2bf(W1[(2*q)*NH + tid]);
            unsigned hi = (unsigned)(unsigned short)f2bf(W1[(2*q+1)*NH + tid]);
            w1p[q] = lo | (hi << 16);
        }
        w1t = W1[32*NH + tid];
        b1u = b1[tid];
    }
    // ---- one-time: W3T[d][j] = W3[j][d] (swizzled) ----
    {
        const int d = tid >> 3, j0 = (tid & 7) * 32;
        const int swd = (d & 7) << 4;
        #pragma unroll
        for (int q = 0; q < 4; ++q) {
            short8 p;
            #pragma unroll
            for (int e = 0; e < 8; ++e) p[e] = f2bf(W3[(j0 + q*8 + e)*ND + d]);
            *(short8*)(W3c + (d << 9) + ((2*j0 + 16*q) ^ swd)) = p;
        }
    }
    // zero pad rows 33..47 of LA (never written again)
    for (int q = tid; q < 15*256; q += 256) ((short*)LA)[33*256 + q] = 0;

    if (tid < ND) xc_s[tid] = x_in[bid*ND + tid];
    if (tid < 3)  csc[tid] = 0.f;
    __syncthreads();

    const float dt = 0.125f;

    for (int n = 0; n < NSTEPS; ++n) {
        const float t0 = (float)n * dt;
        for (int sg = 0; sg < 6; ++sg) {
            // ---- stage input ----
            if (tid < ND) {
                float v = xc_s[tid];
                for (int q = 0; q < sg; ++q) v += dt * Atab[sg][q] * ksb[q][tid];
                xs_s[tid] = v;
            }
            __syncthreads();   // B1
            const float t_eff = 1.0f - (t0 + Ctab[sg]*dt);

            // ---- layer 1 + A-column build (thread = hidden unit tid, all in-reg) ----
            {
                float pre = b1u + t_eff * w1t;
                #pragma unroll
                for (int q = 0; q < 8; ++q) {
                    f32x4 xq = *(const f32x4*)&xs_s[q*4];   // broadcast reads
                    unsigned p0 = w1p[2*q], p1 = w1p[2*q+1];
                    pre += xq[0]*bf_lo(p0) + xq[1]*bf_hi(p0)
                         + xq[2]*bf_lo(p1) + xq[3]*bf_hi(p1);
                }
                const float h1 = fast_tanh(pre);
                const float s1 = 1.f - h1*h1;
                // LA[i][tid] = bf16(W1[i][tid]*s1): column write, 2 lanes/bank
                #pragma unroll
                for (int q = 0; q < 16; ++q) {
                    unsigned p = w1p[q];
                    const int r0 = 2*q, r1 = 2*q+1;
                    *(short*)SWZ(LAc, r0, 2*tid) = f2bf(bf_lo(p)*s1);
                    *(short*)SWZ(LAc, r1, 2*tid) = f2bf(bf_hi(p)*s1);
                }
                ((short*)LA)[32*256 + tid] = f2bf(h1);  // row32: swz==0
            }
            __syncthreads();   // B3

            // ---- T^T GEMM: acc[m][nt]; j = w*64+m*16+g*4+r, i = nt*16+c ----
            f32x4 acc[4][3];
            #pragma unroll
            for (int m = 0; m < 4; ++m)
                #pragma unroll
                for (int q = 0; q < 3; ++q) acc[m][q] = (f32x4){0.f,0.f,0.f,0.f};
            #pragma unroll
            for (int kk = 0; kk < 8; ++kk) {
                const int bo = kk*64 + g*16;
                short8 fA0 = *(const short8*)(LAc + (( 0 + c) << 9) + (bo ^ swc));
                short8 fA1 = *(const short8*)(LAc + ((16 + c) << 9) + (bo ^ swc));
                short8 fA2 = *(const short8*)(LAc + ((32 + c) << 9) + (bo ^ swc));
                #pragma unroll
                for (int m = 0; m < 4; ++m) {
                    acc[m][0] = __builtin_amdgcn_mfma_f32_16x16x32_bf16(w2f[m][kk], fA0, acc[m][0], 0,0,0);
                    acc[m][1] = __builtin_amdgcn_mfma_f32_16x16x32_bf16(w2f[m][kk], fA1, acc[m][1], 0,0,0);
                    acc[m][2] = __builtin_amdgcn_mfma_f32_16x16x32_bf16(w2f[m][kk], fA2, acc[m][2], 0,0,0);
                }
            }
            // h2_pre = T^T[j][32] (col c==0 of Ntile 2) — wave-local exchange
            if (c == 0) {
                #pragma unroll
                for (int m = 0; m < 4; ++m)
                    *(f32x4*)&h2pre[w*64 + m*16 + g*4] = acc[m][2];
            }
            const float h2 = fast_tanh(h2pre[tid] + b2[tid]);  // own-wave DS, in-order
            s2_s[tid] = 1.f - h2*h2;
            __syncthreads();   // B4: all LA reads done -> safe to overwrite
            ((short*)LA)[32*256 + tid] = f2bf(h2);             // row32 := h2
            // ---- Ts^T store: LA[i][j] = T^T[j][i]*s2[j] (8B swizzled writes) ----
            #pragma unroll
            for (int m = 0; m < 4; ++m) {
                const int j0 = w*64 + m*16 + g*4;
                f32x4 s2q = *(const f32x4*)&s2_s[j0];          // broadcast read
                #pragma unroll
                for (int q = 0; q < 2; ++q) {
                    f32x4 v = acc[m][q] * s2q;
                    short4v p;
                    p[0] = f2bf(v[0]); p[1] = f2bf(v[1]); p[2] = f2bf(v[2]); p[3] = f2bf(v[3]);
                    *(short4v*)SWZ(LAc, q*16 + c, 2*j0) = p;
                }
            }
            __syncthreads();   // B5

            // ---- J^T GEMM: J^T[d][i] = sum_j W3T[d][j]*Ts^T[i][j]; tiles over waves ----
            int mt0, nt0, mt1, nt1, np;
            if      (w == 0) { mt0=0; nt0=0; mt1=0; nt1=0; np=1; }
            else if (w == 1) { mt0=0; nt0=1; mt1=1; nt1=2; np=2; }
            else if (w == 2) { mt0=1; nt0=0; mt1=0; nt1=2; np=2; }
            else             { mt0=1; nt0=1; mt1=0; nt1=0; np=1; }
            f32x4 ja = (f32x4){0,0,0,0}, jb = (f32x4){0,0,0,0};
            #pragma unroll
            for (int kk = 0; kk < 8; ++kk) {
                const int bo = kk*64 + g*16;
                short8 a0  = *(const short8*)(W3c + ((mt0*16 + c) << 9) + (bo ^ swc));
                short8 bb0 = *(const short8*)(LAc + ((nt0*16 + c) << 9) + (bo ^ swc));
                ja = __builtin_amdgcn_mfma_f32_16x16x32_bf16(a0, bb0, ja, 0,0,0);
                if (np == 2) {
                    short8 a1  = *(const short8*)(W3c + ((mt1*16 + c) << 9) + (bo ^ swc));
                    short8 bb1 = *(const short8*)(LAc + ((nt1*16 + c) << 9) + (bo ^ swc));
                    jb = __builtin_amdgcn_mfma_f32_16x16x32_bf16(a1, bb1, jb, 0,0,0);
                }
            }

            float frobp = 0.f, trp = 0.f, vfp = 0.f;
            auto jproc = [&](const f32x4& jv, int mt, int nt) {
                if (nt == 2) {
                    if (c == 0) {              // col i==32: primal vf rows d
                        const int d0 = mt*16 + g*4;
                        const f32x4 b3q = *(const f32x4*)(b3 + d0);
                        f32x4 dx;
                        dx[0] = -(jv[0] + b3q[0]); dx[1] = -(jv[1] + b3q[1]);
                        dx[2] = -(jv[2] + b3q[2]); dx[3] = -(jv[3] + b3q[3]);
                        *(f32x4*)&ksb[sg][d0] = dx;
                        vfp += dx[0]*dx[0] + dx[1]*dx[1] + dx[2]*dx[2] + dx[3]*dx[3];
                    }
                } else {                        // d<32, i<32: Jacobian proper
                    frobp += jv[0]*jv[0] + jv[1]*jv[1] + jv[2]*jv[2] + jv[3]*jv[3];
                    if (mt == nt) {
                        const int dd = c - g*4;
                        if (dd >= 0 && dd < 4)
                            trp += (dd==0) ? jv[0] : (dd==1) ? jv[1] : (dd==2) ? jv[2] : jv[3];
                    }
                }
            };
            jproc(ja, mt0, nt0);
            if (np == 2) jproc(jb, mt1, nt1);

            #pragma unroll
            for (int off = 32; off > 0; off >>= 1) {
                frobp += __shfl_down(frobp, off, 64);
                trp   += __shfl_down(trp,   off, 64);
                vfp   += __shfl_down(vfp,   off, 64);
            }
            if (l == 0) { red[w][0] = frobp; red[w][1] = trp; red[w][2] = vfp; }
            __syncthreads();   // B6
            if (tid == 0) {
                float fa = 0.f, fb = 0.f, fc = 0.f;
                #pragma unroll
                for (int q = 0; q < 4; ++q) { fa += red[q][0]; fb += red[q][1]; fc += red[q][2]; }
                sck[sg][0] = -fb;   // d(log_det)/dt = -tr(J)
                sck[sg][1] = fc;    // |dxdt|^2
                sck[sg][2] = fa;    // sum(J*J)
            }
        }

        // ---- carry update (ksb/sck visible via B6; same-thread reads otherwise) ----
        if (tid < ND) {
            float v = xc_s[tid];
            #pragma unroll
            for (int sg = 0; sg < 6; ++sg) v += dt * Btab[sg] * ksb[sg][tid];
            xc_s[tid] = v;
        }
        if (tid == 0) {
            float a = csc[0], b = csc[1], cq = csc[2];
            #pragma unroll
            for (int sg = 0; sg < 6; ++sg) {
                a  += dt * Btab[sg] * sck[sg][0];
                b  += dt * Btab[sg] * sck[sg][1];
                cq += dt * Btab[sg] * sck[sg][2];
            }
            csc[0] = a; csc[1] = b; csc[2] = cq;
        }
        __syncthreads();
    }

    if (tid < ND) out[bid*35 + tid] = xc_s[tid];
    if (tid == 0) {
        out[bid*35 + 32] = csc[0];
        out[bid*35 + 33] = csc[1];
        out[bid*35 + 34] = csc[2];
    }
}

extern "C" void kernel_launch(void* const* d_in, const int* in_sizes, int n_in,
                              void* d_out, int out_size, void* d_ws, size_t ws_size,
                              hipStream_t stream) {
    const float* x  = (const float*)d_in[0];
    const float* W1 = (const float*)d_in[1];
    const float* b1 = (const float*)d_in[2];
    const float* W2 = (const float*)d_in[3];
    const float* b2 = (const float*)d_in[4];
    const float* W3 = (const float*)d_in[5];
    const float* b3 = (const float*)d_in[6];
    float* outp = (float*)d_out;
    hipLaunchKernelGGL(node_kernel, dim3(NB), dim3(256), 0, stream,
                       x, W1, b1, W2, b2, W3, b3, outp);
}